// Round 4
// baseline (404.883 us; speedup 1.0000x reference)
//
#include <hip/hip_runtime.h>
#include <math.h>

#define HW 256
#define CDIM 64
#define NHEAD 8
#define CFULL 512
#define BATCH 4
#define TFRAMES 64
#define NKEY (TFRAMES*HW)            // 16384
#define NSPLIT 16
#define KEYS_PER_SPLIT (NKEY/NSPLIT) // 1024
#define CHUNK 64
#define NCHUNK (KEYS_PER_SPLIT/CHUNK) // 16

#define KLOG10K_64 0.14391156634543589f  // ln(10000)/64

#define KP 68   // attn Ks LDS pad (halves)
#define VP 72   // attn Vt LDS pad (halves)
#define PA 72   // gemm LDS pitch (halves): 64 + 8

typedef _Float16 half4  __attribute__((ext_vector_type(4)));
typedef _Float16 half2v __attribute__((ext_vector_type(2)));
typedef float    floatx4 __attribute__((ext_vector_type(4)));

#define MFMA16(a,b,c) __builtin_amdgcn_mfma_f32_16x16x16f16((a),(b),(c),0,0,0)

// ---------------- ws layout (float offsets) ----------------
// wq_h   : [0]        1536*512 f16 = 393216 fl
// wp_h   : [393216]   512*512 f16 (cols permuted k'=head*64+ch) = 131072 fl
// xt_h   : [524288]   4*256*512 f16 = 262144 fl
// q      : [786432]   524288 f32  (roped pos63)   [bm][p][ch]
// kn     : [1310720]  524288 f32  (roped pos63)   [bm][p][ch]
// vn     : [1835008]  524288 f32                  [bm][p][ch]
// o_part : [2359296]  32*16*64*256 f16 = 4194304 fl   [bm][s][ch][p]
// ml     : [6553600]  32*16*2*256 f32 = 262144 fl     [bm][s][{m,l}][p]
// omt_h  : [6815744]  4*256*512 f16 = 262144 fl       [b][p][head*64+ch]
// end 7077888 floats = 28.3 MB

// ---- Kernel 1: fused weight-norm (+wp col permute) and x-transpose ----
__global__ void k_prep(const float* __restrict__ wqkv, const float* __restrict__ wproj,
                       const float* __restrict__ x,
                       _Float16* __restrict__ wq_h, _Float16* __restrict__ wp_h,
                       _Float16* __restrict__ xt_h) {
    int bid = blockIdx.x;
    int t = threadIdx.x;
    if (bid < 2048) {
        int row = bid;
        const float* src = (row < 1536) ? wqkv + row*CFULL : wproj + (row-1536)*CFULL;
        float a = src[t], b = src[t+256];
        float v = a*a + b*b;
        #pragma unroll
        for (int o = 32; o >= 1; o >>= 1) v += __shfl_down(v, o, 64);
        __shared__ float red[4];
        if ((t & 63) == 0) red[t >> 6] = v;
        __syncthreads();
        float ss = red[0] + red[1] + red[2] + red[3];
        float norm = sqrtf(ss);
        const float s512 = 22.627416997969522f;
        float scale = 1.0f / ((1e-4f + norm / s512) * s512);
        if (row < 1536) {
            wq_h[row*CFULL + t]       = (_Float16)(a*scale);
            wq_h[row*CFULL + t + 256] = (_Float16)(b*scale);
        } else {
            int r2 = row - 1536;
            int kp_ = (t & 7)*64 + (t >> 3);   // k' for ic=t ; ic=t+256 -> k'+32
            wp_h[r2*CFULL + kp_]      = (_Float16)(a*scale);
            wp_h[r2*CFULL + kp_ + 32] = (_Float16)(b*scale);
        }
    } else {
        int xb = bid - 2048;            // 128 blocks
        int pb = xb & 3, cb = (xb >> 2) & 7, b = xb >> 5;
        int p  = pb*64 + (t & 63);
        int c0 = cb*64 + (t >> 6)*16;
        half4 h[4];
        #pragma unroll
        for (int j = 0; j < 16; j++) {
            float val = x[((long)(b*CFULL + c0 + j))*HW + p];
            h[j >> 2][j & 3] = (_Float16)val;
        }
        _Float16* dst = xt_h + ((long)(b*HW + p))*CFULL + c0;
        #pragma unroll
        for (int j = 0; j < 4; j++) *(half4*)(dst + j*4) = h[j];
    }
}

// ---- Kernel 2: QKV projection GEMM (MFMA) + RoPE(pos63) epilogue ----
__global__ __launch_bounds__(256) void k_gemm_qkv(
        const _Float16* __restrict__ wq_h, const _Float16* __restrict__ xt_h,
        float* __restrict__ q, float* __restrict__ kn, float* __restrict__ vn) {
    int bx = blockIdx.x;
    int by = blockIdx.y;
    int b  = blockIdx.z;
    int t  = threadIdx.x;
    int wave = t >> 6, lane = t & 63, ln = lane & 15, quad = lane >> 4;
    __shared__ _Float16 As[64*PA];
    __shared__ _Float16 Bs[64*PA];
    int obase = bx*64, pbase = by*64;
    int lrow = t >> 2, lseg = t & 3;
    const _Float16* ag = wq_h + (long)(obase + lrow)*CFULL + lseg*16;
    const _Float16* bg = xt_h + (long)(b*HW + pbase + lrow)*CFULL + lseg*16;
    uint4 ar0 = *(const uint4*)ag,     ar1 = *(const uint4*)(ag + 8);
    uint4 br0 = *(const uint4*)bg,     br1 = *(const uint4*)(bg + 8);
    floatx4 acc[4];
    #pragma unroll
    for (int nt = 0; nt < 4; nt++) acc[nt] = (floatx4){0.f,0.f,0.f,0.f};
    for (int kc = 0; kc < 8; kc++) {
        __syncthreads();
        *(uint4*)&As[lrow*PA + lseg*16]     = ar0;
        *(uint4*)&As[lrow*PA + lseg*16 + 8] = ar1;
        *(uint4*)&Bs[lrow*PA + lseg*16]     = br0;
        *(uint4*)&Bs[lrow*PA + lseg*16 + 8] = br1;
        __syncthreads();
        if (kc < 7) {
            const _Float16* an = ag + (kc+1)*64;
            const _Float16* bn = bg + (kc+1)*64;
            ar0 = *(const uint4*)an; ar1 = *(const uint4*)(an + 8);
            br0 = *(const uint4*)bn; br1 = *(const uint4*)(bn + 8);
        }
        #pragma unroll
        for (int ks = 0; ks < 4; ks++) {
            half4 af = *(const half4*)&As[(wave*16 + ln)*PA + ks*16 + quad*4];
            #pragma unroll
            for (int nt = 0; nt < 4; nt++) {
                half4 bf = *(const half4*)&Bs[(nt*16 + ln)*PA + ks*16 + quad*4];
                acc[nt] = MFMA16(af, bf, acc[nt]);
            }
        }
    }
    int sec  = obase >> 9;
    int head = (obase >> 6) & 7;
    int bm   = b*NHEAD + head;
    int ch0  = wave*16 + quad*4;
    if (sec == 2) {
        #pragma unroll
        for (int nt = 0; nt < 4; nt++) {
            int p = pbase + nt*16 + ln;
            float4 o4; o4.x = acc[nt][0]; o4.y = acc[nt][1]; o4.z = acc[nt][2]; o4.w = acc[nt][3];
            *(float4*)&vn[((long)(bm*HW + p))*CDIM + ch0] = o4;
        }
    } else {
        float* dst = (sec == 0) ? q : kn;
        float fr0 = __expf(-(float)ch0       * KLOG10K_64);
        float fr1 = __expf(-(float)(ch0 + 2) * KLOG10K_64);
        float s0, c0, s1, c1;
        __sincosf(63.0f*fr0, &s0, &c0);
        __sincosf(63.0f*fr1, &s1, &c1);
        #pragma unroll
        for (int nt = 0; nt < 4; nt++) {
            int p = pbase + nt*16 + ln;
            float4 o4;
            o4.x = acc[nt][0]*c0 - acc[nt][1]*s0;
            o4.y = acc[nt][0]*s0 + acc[nt][1]*c0;
            o4.z = acc[nt][2]*c1 - acc[nt][3]*s1;
            o4.w = acc[nt][2]*s1 + acc[nt][3]*c1;
            *(float4*)&dst[((long)(bm*HW + p))*CDIM + ch0] = o4;
        }
    }
}

// ---- Kernel 3: MFMA flash attention, double-buffered LDS, NSPLIT=16 ----
__global__ __launch_bounds__(512, 4) void k_attn(
        const float* __restrict__ q, const float* __restrict__ kc, const float* __restrict__ vc,
        const float* __restrict__ kn, const float* __restrict__ vn,
        _Float16* __restrict__ o_part, float* __restrict__ ml) {
    const int bm = blockIdx.x;   // 32
    const int s  = blockIdx.y;   // 16
    const int t  = threadIdx.x;
    const int wave = t >> 6;
    const int lane = t & 63;
    const int ln   = lane & 15;
    const int quad = lane >> 4;
    const int qbase = wave * 32;

    __shared__ _Float16 Ks[2][CHUNK*KP];
    __shared__ _Float16 Vt[2][CDIM*VP];

    // Q fragments (scale 1/8 folded)
    half4 qf[2][4];
    #pragma unroll
    for (int qt = 0; qt < 2; qt++)
        #pragma unroll
        for (int ks = 0; ks < 4; ks++) {
            const float* qp = q + ((long)(bm*HW + qbase + qt*16 + ln))*CDIM + ks*16 + quad*4;
            float4 f = *(const float4*)qp;
            half4 h;
            h[0] = (_Float16)(f.x*0.125f); h[1] = (_Float16)(f.y*0.125f);
            h[2] = (_Float16)(f.z*0.125f); h[3] = (_Float16)(f.w*0.125f);
            qf[qt][ks] = h;
        }

    floatx4 oacc[4][2];
    #pragma unroll
    for (int ct = 0; ct < 4; ct++)
        #pragma unroll
        for (int qt = 0; qt < 2; qt++)
            oacc[ct][qt] = (floatx4){0.f,0.f,0.f,0.f};
    float m_[2] = {-1e30f, -1e30f};
    float l_[2] = {0.f, 0.f};

    // staging roles (fixed per thread)
    const int key0 = t >> 4;          // 0..31 (and key0+32)
    const int chk  = (t & 15) * 4;
    const int kp   = t & 31;
    const int chv  = (t >> 5) * 4;
    // hoisted rope frequencies (constant per lane)
    const float fr0 = __expf(-(float)chk       * KLOG10K_64);
    const float fr1 = __expf(-(float)(chk + 2) * KLOG10K_64);

    float4 ka, kb, va, vb;   // prefetch registers

    auto prefetch = [&](int c) -> int {
        int g0 = s*KEYS_PER_SPLIT + c*CHUNK;
        int tfr = g0 >> 8, poff = g0 & 255;
        const float *ksrc, *vsrc;
        if (tfr < 63) {
            long base = ((long)((bm*63 + tfr)*HW + poff))*CDIM;
            ksrc = kc + base; vsrc = vc + base;
        } else {
            long base = ((long)(bm*HW + poff))*CDIM;
            ksrc = kn + base; vsrc = vn + base;
        }
        ka = *(const float4*)(ksrc + key0*CDIM + chk);
        kb = *(const float4*)(ksrc + (key0+32)*CDIM + chk);
        va = *(const float4*)(vsrc + (2*kp  )*CDIM + chv);
        vb = *(const float4*)(vsrc + (2*kp+1)*CDIM + chv);
        return tfr;
    };

    auto write_buf = [&](int d, int tfr) {
        float4 fka = ka, fkb = kb;
        if (tfr < 63) {   // cached K needs rope; kn already roped at pos 63
            float tp = (float)tfr;
            float s0, c0, s1, c1;
            __sincosf(tp*fr0, &s0, &c0);
            __sincosf(tp*fr1, &s1, &c1);
            float4 r;
            r.x = fka.x*c0 - fka.y*s0; r.y = fka.x*s0 + fka.y*c0;
            r.z = fka.z*c1 - fka.w*s1; r.w = fka.z*s1 + fka.w*c1;
            fka = r;
            r.x = fkb.x*c0 - fkb.y*s0; r.y = fkb.x*s0 + fkb.y*c0;
            r.z = fkb.z*c1 - fkb.w*s1; r.w = fkb.z*s1 + fkb.w*c1;
            fkb = r;
        }
        half4 h;
        h[0]=(_Float16)fka.x; h[1]=(_Float16)fka.y; h[2]=(_Float16)fka.z; h[3]=(_Float16)fka.w;
        *(half4*)&Ks[d][key0*KP + chk] = h;
        h[0]=(_Float16)fkb.x; h[1]=(_Float16)fkb.y; h[2]=(_Float16)fkb.z; h[3]=(_Float16)fkb.w;
        *(half4*)&Ks[d][(key0+32)*KP + chk] = h;
        float av[4] = {va.x,va.y,va.z,va.w};
        float bv[4] = {vb.x,vb.y,vb.z,vb.w};
        #pragma unroll
        for (int i = 0; i < 4; i++) {
            half2v hv; hv[0] = (_Float16)av[i]; hv[1] = (_Float16)bv[i];
            *(half2v*)&Vt[d][(chv+i)*VP + 2*kp] = hv;
        }
    };

    int tfr0 = prefetch(0);
    write_buf(0, tfr0);
    int tfr_next = 0;

    for (int c = 0; c < NCHUNK; c++) {
        const int buf = c & 1;
        if (c+1 < NCHUNK) tfr_next = prefetch(c+1);   // loads in flight during compute
        __syncthreads();                              // buf writes visible

        floatx4 sacc[4][2];
        #pragma unroll
        for (int kt = 0; kt < 4; kt++)
            #pragma unroll
            for (int qt = 0; qt < 2; qt++)
                sacc[kt][qt] = (floatx4){0.f,0.f,0.f,0.f};
        #pragma unroll
        for (int ks = 0; ks < 4; ks++) {
            half4 kf[4];
            #pragma unroll
            for (int kt = 0; kt < 4; kt++)
                kf[kt] = *(const half4*)&Ks[buf][(kt*16 + ln)*KP + ks*16 + quad*4];
            #pragma unroll
            for (int kt = 0; kt < 4; kt++)
                #pragma unroll
                for (int qt = 0; qt < 2; qt++)
                    sacc[kt][qt] = MFMA16(kf[kt], qf[qt][ks], sacc[kt][qt]);
        }

        half4 ptf[4][2];
        #pragma unroll
        for (int qt = 0; qt < 2; qt++) {
            float tmax = -1e30f;
            #pragma unroll
            for (int kt = 0; kt < 4; kt++)
                #pragma unroll
                for (int r = 0; r < 4; r++)
                    tmax = fmaxf(tmax, sacc[kt][qt][r]);
            tmax = fmaxf(tmax, __shfl_xor(tmax, 16, 64));
            tmax = fmaxf(tmax, __shfl_xor(tmax, 32, 64));
            float mnew  = fmaxf(m_[qt], tmax);
            float alpha = __expf(m_[qt] - mnew);
            float lsum = 0.f;
            #pragma unroll
            for (int kt = 0; kt < 4; kt++) {
                half4 ph;
                #pragma unroll
                for (int r = 0; r < 4; r++) {
                    float p = __expf(sacc[kt][qt][r] - mnew);
                    lsum += p;
                    ph[r] = (_Float16)p;
                }
                ptf[kt][qt] = ph;
            }
            lsum += __shfl_xor(lsum, 16, 64);
            lsum += __shfl_xor(lsum, 32, 64);
            l_[qt] = l_[qt]*alpha + lsum;
            m_[qt] = mnew;
            #pragma unroll
            for (int ct = 0; ct < 4; ct++)
                #pragma unroll
                for (int r = 0; r < 4; r++)
                    oacc[ct][qt][r] *= alpha;
        }

        #pragma unroll
        for (int kt = 0; kt < 4; kt++) {
            half4 vf[4];
            #pragma unroll
            for (int ct = 0; ct < 4; ct++)
                vf[ct] = *(const half4*)&Vt[buf][(ct*16 + ln)*VP + kt*16 + quad*4];
            #pragma unroll
            for (int ct = 0; ct < 4; ct++)
                #pragma unroll
                for (int qt = 0; qt < 2; qt++)
                    oacc[ct][qt] = MFMA16(vf[ct], ptf[kt][qt], oacc[ct][qt]);
        }

        if (c+1 < NCHUNK) write_buf((c+1) & 1, tfr_next);  // other buffer: no barrier needed
    }

    long ob = ((long)(bm*NSPLIT + s)) * CDIM * HW;
    #pragma unroll
    for (int ct = 0; ct < 4; ct++)
        #pragma unroll
        for (int qt = 0; qt < 2; qt++)
            #pragma unroll
            for (int r = 0; r < 4; r++)
                o_part[ob + (long)(ct*16 + quad*4 + r)*HW + qbase + qt*16 + ln] =
                    (_Float16)oacc[ct][qt][r];
    long mb = ((long)(bm*NSPLIT + s)) * 2 * HW;
    if (quad == 0) {
        #pragma unroll
        for (int qt = 0; qt < 2; qt++) {
            int qq = qbase + qt*16 + ln;
            ml[mb + qq]      = m_[qt];
            ml[mb + HW + qq] = l_[qt];
        }
    }
}

// ---- Kernel 4: combine split partials -> omt_h[b][p][head*64+ch] f16 ----
__global__ void k_combine(const _Float16* __restrict__ o_part, const float* __restrict__ ml,
                          _Float16* __restrict__ omt_h) {
    int bm  = blockIdx.x;   // 32
    int chg = blockIdx.y;   // 16 groups of 4 ch
    int p   = threadIdx.x;
    float ms[NSPLIT], ls[NSPLIT];
    float mmax = -1e30f;
    #pragma unroll
    for (int s2 = 0; s2 < NSPLIT; s2++) {
        long mb = ((long)(bm*NSPLIT + s2)) * 2 * HW;
        ms[s2] = ml[mb + p];
        ls[s2] = ml[mb + HW + p];
        mmax = fmaxf(mmax, ms[s2]);
    }
    float wgt[NSPLIT];
    float wsum = 0.f;
    #pragma unroll
    for (int s2 = 0; s2 < NSPLIT; s2++) { wgt[s2] = __expf(ms[s2]-mmax); wsum += wgt[s2]*ls[s2]; }
    float inv = 1.0f / wsum;
    float acc[4] = {0.f, 0.f, 0.f, 0.f};
    #pragma unroll
    for (int s2 = 0; s2 < NSPLIT; s2++) {
        float w = wgt[s2];
        const _Float16* src = o_part + (((long)(bm*NSPLIT + s2))*CDIM + chg*4)*HW + p;
        #pragma unroll
        for (int i = 0; i < 4; i++) acc[i] += w * (float)src[(long)i*HW];
    }
    int b = bm >> 3, head = bm & 7;
    half4 h;
    #pragma unroll
    for (int i = 0; i < 4; i++) h[i] = (_Float16)(acc[i]*inv);
    *(half4*)(omt_h + ((long)(b*HW + p))*CFULL + head*64 + chg*4) = h;
}

// ---- Kernel 5: output projection GEMM (MFMA) + mp_sum residual ----
__global__ __launch_bounds__(256) void k_gemm_proj(
        const _Float16* __restrict__ wp_h, const _Float16* __restrict__ omt_h,
        const float* __restrict__ x, float* __restrict__ out) {
    int bx = blockIdx.x;
    int by = blockIdx.y;
    int b  = blockIdx.z;
    int t  = threadIdx.x;
    int wave = t >> 6, lane = t & 63, ln = lane & 15, quad = lane >> 4;
    __shared__ _Float16 As[64*PA];
    __shared__ _Float16 Bs[64*PA];
    int obase = bx*64, pbase = by*64;
    int lrow = t >> 2, lseg = t & 3;
    const _Float16* ag = wp_h  + (long)(obase + lrow)*CFULL + lseg*16;
    const _Float16* bg = omt_h + (long)(b*HW + pbase + lrow)*CFULL + lseg*16;
    uint4 ar0 = *(const uint4*)ag, ar1 = *(const uint4*)(ag + 8);
    uint4 br0 = *(const uint4*)bg, br1 = *(const uint4*)(bg + 8);
    floatx4 acc[4];
    #pragma unroll
    for (int nt = 0; nt < 4; nt++) acc[nt] = (floatx4){0.f,0.f,0.f,0.f};
    for (int kc = 0; kc < 8; kc++) {
        __syncthreads();
        *(uint4*)&As[lrow*PA + lseg*16]     = ar0;
        *(uint4*)&As[lrow*PA + lseg*16 + 8] = ar1;
        *(uint4*)&Bs[lrow*PA + lseg*16]     = br0;
        *(uint4*)&Bs[lrow*PA + lseg*16 + 8] = br1;
        __syncthreads();
        if (kc < 7) {
            const _Float16* an = ag + (kc+1)*64;
            const _Float16* bn = bg + (kc+1)*64;
            ar0 = *(const uint4*)an; ar1 = *(const uint4*)(an + 8);
            br0 = *(const uint4*)bn; br1 = *(const uint4*)(bn + 8);
        }
        #pragma unroll
        for (int ks = 0; ks < 4; ks++) {
            half4 af = *(const half4*)&As[(wave*16 + ln)*PA + ks*16 + quad*4];
            #pragma unroll
            for (int nt = 0; nt < 4; nt++) {
                half4 bf = *(const half4*)&Bs[(nt*16 + ln)*PA + ks*16 + quad*4];
                acc[nt] = MFMA16(af, bf, acc[nt]);
            }
        }
    }
    const float inv_mp = 1.3130643285972254f;
    int o0 = obase + wave*16 + quad*4;
    #pragma unroll
    for (int nt = 0; nt < 4; nt++) {
        int p = pbase + nt*16 + ln;
        #pragma unroll
        for (int r = 0; r < 4; r++) {
            long idx = ((long)(b*CFULL + o0 + r))*HW + p;
            out[idx] = (x[idx]*0.7f + acc[nt][r]*0.3f) * inv_mp;
        }
    }
}

extern "C" void kernel_launch(void* const* d_in, const int* in_sizes, int n_in,
                              void* d_out, int out_size, void* d_ws, size_t ws_size,
                              hipStream_t stream) {
    const float* x     = (const float*)d_in[0];
    const float* kc    = (const float*)d_in[1];
    const float* vc    = (const float*)d_in[2];
    const float* wqkv  = (const float*)d_in[3];
    const float* wproj = (const float*)d_in[4];
    float* out = (float*)d_out;
    float* ws  = (float*)d_ws;

    _Float16* wq_h  = (_Float16*)ws;
    _Float16* wp_h  = (_Float16*)(ws + 393216);
    _Float16* xt_h  = (_Float16*)(ws + 524288);
    float* q        = ws + 786432;
    float* kn       = ws + 1310720;
    float* vn       = ws + 1835008;
    _Float16* o_part= (_Float16*)(ws + 2359296);
    float* ml       = ws + 6553600;
    _Float16* omt_h = (_Float16*)(ws + 6815744);

    hipLaunchKernelGGL(k_prep,      dim3(2176),       dim3(256), 0, stream, wqkv, wproj, x, wq_h, wp_h, xt_h);
    hipLaunchKernelGGL(k_gemm_qkv,  dim3(24,4,4),     dim3(256), 0, stream, wq_h, xt_h, q, kn, vn);
    hipLaunchKernelGGL(k_attn,      dim3(32,NSPLIT),  dim3(512), 0, stream, q, kc, vc, kn, vn, o_part, ml);
    hipLaunchKernelGGL(k_combine,   dim3(32,16),      dim3(256), 0, stream, o_part, ml, omt_h);
    hipLaunchKernelGGL(k_gemm_proj, dim3(8,4,4),      dim3(256), 0, stream, wp_h, omt_h, x, out);
}